// Round 5
// baseline (156.307 us; speedup 1.0000x reference)
//
#include <hip/hip_runtime.h>

// Problem: B=2,H=16,S=4096,D=64, NSQ=NSK=2048.
// scale = S*S/(NSQ*NSK) = 4, resid = S/NSK = 2. K and mask inputs are unused.
// Per (b,h): Qs=Q[iq] (2048x64), Vs=V[ik] (2048x64).
//   Qsm = row_softmax(Qs) (no max-sub: fp32 N(0,1) inputs, exp can't overflow);
//   E = exp(Qsm); C[d] = sum_s E[s,d]; M[d,e] = sum_s E[s,d]*Vs[s,e];
//   G[d,e] = 4*M[d,e]/C[d];  ac = Qsm @ G + 2*Vs;  out.at[iq].add(ac).
// 3-kernel pipeline:
//   kA (1024 blk): per-64-row partial M (MFMA, plain stores) + partial C; also
//                  stores Qsm bf16 row-major to ws for kC reuse.
//   kB (128 blk):  reduce 32 partials -> G bf16 d-major (once per bh, not per kC block).
//   kC (1024 blk): LDS-stage Qsm + G, ac = Qsm @ G + 2*Vs via MFMA, atomic scatter.
constexpr int S    = 4096;
constexpr int D    = 64;
constexpr int NSQ  = 2048;
constexpr int BH   = 32;             // B*H
constexpr int SD   = S * D;

constexpr int SPA  = 32;             // kA splits per bh -> 1024 blocks (4/CU)
constexpr int RPBA = NSQ / SPA;      // rows per kA block = 64
constexpr int ITA  = 4;              // staging iters (4 rows/wave/iter)
constexpr int PEA  = 66;             // Et/Vt pitch (u16): 33-dword stride -> conflict-free

constexpr int SPC  = 32;             // kC splits per bh -> 1024 blocks
constexpr int RPBC = NSQ / SPC;      // rows per kC block = 64
constexpr int PQ   = 68;             // Qs/Gt pitch (u16): 34-dword stride -> 2-way (free)

using f32x16 = __attribute__((ext_vector_type(16))) float;
using s16x8  = __attribute__((ext_vector_type(8)))  short;  // 8 bf16 (4 VGPRs)

#define DEV static __device__ __forceinline__

DEV unsigned short f2bf(float f) {  // round-to-nearest-even bf16
    unsigned x = __builtin_bit_cast(unsigned, f);
    x += 0x7fffu + ((x >> 16) & 1u);
    return (unsigned short)(x >> 16);
}

DEV s16x8 load_frag(const unsigned short* p) {  // 8 contiguous bf16 from LDS (4B-aligned)
    const unsigned* u = (const unsigned*)p;
    union { unsigned w[4]; s16x8 v; } r;
    r.w[0] = u[0]; r.w[1] = u[1]; r.w[2] = u[2]; r.w[3] = u[3];
    return r.v;
}

// Kernel A: partial M = E^T @ V and partial C over this block's 64 rows; Qsm -> ws.
__global__ __launch_bounds__(256) void
kA(const float* __restrict__ Q, const float* __restrict__ V,
   const int* __restrict__ iq, const int* __restrict__ ik,
   float* __restrict__ Mp, float* __restrict__ Cp,
   unsigned short* __restrict__ Qsw) {
    __shared__ unsigned short Et[64 * PEA];
    __shared__ unsigned short Vt[64 * PEA];
    __shared__ float Cl[4][256];
    __shared__ int iqL[RPBA], ikL[RPBA];

    const int bh   = blockIdx.x / SPA;
    const int sp   = blockIdx.x % SPA;
    const int lane = threadIdx.x & 63;
    const int wave = threadIdx.x >> 6;
    const int rq   = lane >> 4;        // row within staging quad
    const int c    = lane & 15;        // d-quad

    const int rbase = sp * RPBA;
    if (threadIdx.x < RPBA) {
        iqL[threadIdx.x] = iq[rbase + threadIdx.x];
        ikL[threadIdx.x] = ik[rbase + threadIdx.x];
    }
    __syncthreads();

    const float* Qb = Q + (size_t)bh * SD;
    const float* Vb = V + (size_t)bh * SD;

    float c4[4] = {0.f, 0.f, 0.f, 0.f};
    #pragma unroll
    for (int it = 0; it < ITA; ++it) {
        const int sl = wave * 16 + it * 4 + rq;     // local row 0..63
        const int qi = iqL[sl];
        const int ki = ikL[sl];
        const float4 qv = *(const float4*)&Qb[qi * D + 4 * c];
        const float4 vv = *(const float4*)&Vb[ki * D + 4 * c];
        const float e0 = __expf(qv.x), e1 = __expf(qv.y),
                    e2 = __expf(qv.z), e3 = __expf(qv.w);
        float s = (e0 + e1) + (e2 + e3);
        s += __shfl_xor(s, 1); s += __shfl_xor(s, 2);
        s += __shfl_xor(s, 4); s += __shfl_xor(s, 8);   // 16-lane row group
        const float inv = 1.0f / s;
        const float q0 = e0 * inv, q1 = e1 * inv, q2 = e2 * inv, q3 = e3 * inv;
        const float E0 = __expf(q0), E1 = __expf(q1),
                    E2 = __expf(q2), E3 = __expf(q3);
        c4[0] += E0; c4[1] += E1; c4[2] += E2; c4[3] += E3;
        Et[(4 * c + 0) * PEA + sl] = f2bf(E0);
        Et[(4 * c + 1) * PEA + sl] = f2bf(E1);
        Et[(4 * c + 2) * PEA + sl] = f2bf(E2);
        Et[(4 * c + 3) * PEA + sl] = f2bf(E3);
        Vt[(4 * c + 0) * PEA + sl] = f2bf(vv.x);
        Vt[(4 * c + 1) * PEA + sl] = f2bf(vv.y);
        Vt[(4 * c + 2) * PEA + sl] = f2bf(vv.z);
        Vt[(4 * c + 3) * PEA + sl] = f2bf(vv.w);
        uint2 pk;   // Qsm bf16 row-major -> ws (512B contiguous per instr)
        pk.x = (unsigned)f2bf(q0) | ((unsigned)f2bf(q1) << 16);
        pk.y = (unsigned)f2bf(q2) | ((unsigned)f2bf(q3) << 16);
        *(uint2*)&Qsw[((size_t)bh * NSQ + rbase + sl) * 64 + 4 * c] = pk;
    }
    Cl[wave][lane * 4 + 0] = c4[0];
    Cl[wave][lane * 4 + 1] = c4[1];
    Cl[wave][lane * 4 + 2] = c4[2];
    Cl[wave][lane * 4 + 3] = c4[3];
    __syncthreads();

    // MFMA: wave -> one 32x32 tile of M, K = 64
    const int d0 = (wave & 1) * 32, n0 = (wave >> 1) * 32;
    const int m  = lane & 31, h = lane >> 5;
    f32x16 acc = {0,0,0,0,0,0,0,0,0,0,0,0,0,0,0,0};
    #pragma unroll
    for (int t = 0; t < RPBA / 16; ++t) {
        s16x8 a = load_frag(&Et[(d0 + m) * PEA + t * 16 + h * 8]);
        s16x8 b = load_frag(&Vt[(n0 + m) * PEA + t * 16 + h * 8]);
        acc = __builtin_amdgcn_mfma_f32_32x32x16_bf16(a, b, acc, 0, 0, 0);
    }
    // C/D layout: col = lane&31, row = (reg&3) + 8*(reg>>2) + 4*(lane>>5)
    float* Mb = Mp + ((size_t)bh * SPA + sp) * 4096;
    #pragma unroll
    for (int r = 0; r < 16; ++r) {
        const int row = (r & 3) + 8 * (r >> 2) + 4 * h;
        Mb[(d0 + row) * 64 + n0 + m] = acc[r];
    }
    if (wave == 0) {   // lane -> d; fold 16-lane-group partials over waves/row-quads
        const int cc = lane >> 2, j = lane & 3;
        float cs = 0.f;
        #pragma unroll
        for (int w = 0; w < 4; ++w)
            #pragma unroll
            for (int r = 0; r < 4; ++r)
                cs += Cl[w][(16 * r + cc) * 4 + j];
        Cp[((size_t)bh * SPA + sp) * 64 + lane] = cs;
    }
}

// Kernel B: reduce 32 partials -> G[d][e] = 4*M[d][e]/C[d], bf16 d-major. 128 blocks.
__global__ __launch_bounds__(256) void
kB(const float* __restrict__ Mp, const float* __restrict__ Cp,
   unsigned short* __restrict__ Gtw) {
    __shared__ float Cf[64];
    const int bh = blockIdx.x >> 2;
    const int qr = blockIdx.x & 3;

    if (threadIdx.x < 64) {
        float cs = 0.f;
        #pragma unroll 8
        for (int p = 0; p < SPA; ++p)
            cs += Cp[((size_t)bh * SPA + p) * 64 + threadIdx.x];
        Cf[threadIdx.x] = cs;
    }
    __syncthreads();

    const int l = qr * 1024 + threadIdx.x * 4;    // 4 cells, same d
    const int d = l >> 6;
    const float* MpB = Mp + (size_t)bh * SPA * 4096;
    float4 ms = {0.f, 0.f, 0.f, 0.f};
    #pragma unroll 8
    for (int p = 0; p < SPA; ++p) {
        const float4 t = *(const float4*)&MpB[p * 4096 + l];
        ms.x += t.x; ms.y += t.y; ms.z += t.z; ms.w += t.w;
    }
    const float g = 4.0f / Cf[d];
    uint2 pk;
    pk.x = (unsigned)f2bf(ms.x * g) | ((unsigned)f2bf(ms.y * g) << 16);
    pk.y = (unsigned)f2bf(ms.z * g) | ((unsigned)f2bf(ms.w * g) << 16);
    *(uint2*)&Gtw[(size_t)bh * 4096 + l] = pk;    // coalesced d-major store
}

// Kernel C: ac = Qsm @ G + 2*Vs, scatter-add into out.
__global__ __launch_bounds__(256) void
kC(const float* __restrict__ V,
   const int* __restrict__ iq, const int* __restrict__ ik,
   const unsigned short* __restrict__ Qsw, const unsigned short* __restrict__ Gtw,
   float* __restrict__ out) {
    __shared__ unsigned short Qs[RPBC * PQ];   // Qs[row][d]
    __shared__ unsigned short Gt[64 * PQ];     // Gt[e][d]
    __shared__ int iqL[RPBC], ikL[RPBC];

    const int bh   = blockIdx.x / SPC;
    const int sp   = blockIdx.x % SPC;
    const int lane = threadIdx.x & 63;
    const int wave = threadIdx.x >> 6;
    const int rbase = sp * RPBC;

    if (threadIdx.x < RPBC) {
        iqL[threadIdx.x] = iq[rbase + threadIdx.x];
        ikL[threadIdx.x] = ik[rbase + threadIdx.x];
    }

    // G: load d-major (coalesced), transpose into LDS e-major (tiny u16 scatter).
    {
        const int l0 = threadIdx.x * 16;            // 16 cells, d = tid>>2 const
        const int d  = l0 >> 6;
        const uint4 w0 = *(const uint4*)&Gtw[(size_t)bh * 4096 + l0];
        const uint4 w1 = *(const uint4*)&Gtw[(size_t)bh * 4096 + l0 + 8];
        const unsigned wv[8] = {w0.x, w0.y, w0.z, w0.w, w1.x, w1.y, w1.z, w1.w};
        const int e0 = l0 & 63;
        #pragma unroll
        for (int j = 0; j < 8; ++j) {
            Gt[(e0 + 2 * j + 0) * PQ + d] = (unsigned short)(wv[j] & 0xffffu);
            Gt[(e0 + 2 * j + 1) * PQ + d] = (unsigned short)(wv[j] >> 16);
        }
    }
    // Qsm rows: straight copy with pitch insertion (8B-aligned uint2 stores).
    {
        const int l0  = threadIdx.x * 16;           // u16 index into 64x64 block
        const int row = l0 >> 6, col = l0 & 63;
        const uint4 w0 = *(const uint4*)&Qsw[((size_t)bh * NSQ + rbase) * 64 + l0];
        const uint4 w1 = *(const uint4*)&Qsw[((size_t)bh * NSQ + rbase) * 64 + l0 + 8];
        *(uint2*)&Qs[row * PQ + col + 0] = make_uint2(w0.x, w0.y);
        *(uint2*)&Qs[row * PQ + col + 4] = make_uint2(w0.z, w0.w);
        *(uint2*)&Qs[row * PQ + col + 8] = make_uint2(w1.x, w1.y);
        *(uint2*)&Qs[row * PQ + col + 12] = make_uint2(w1.z, w1.w);
    }
    __syncthreads();

    const float* Vb = V + (size_t)bh * SD;
    float*       Ob = out + (size_t)bh * SD;

    // MFMA: wave -> 32x32 tile, K = 64; residual 2*Vs folded into C operand.
    const int m0 = (wave & 1) * 32, n0 = (wave >> 1) * 32;
    const int m  = lane & 31, h = lane >> 5;
    f32x16 acc;
    #pragma unroll
    for (int r = 0; r < 16; ++r) {
        const int row = (r & 3) + 8 * (r >> 2) + 4 * h;
        const int ki  = ikL[m0 + row];
        acc[r] = 2.0f * Vb[ki * D + n0 + m];
    }
    #pragma unroll
    for (int t = 0; t < RPBC / 16; ++t) {
        s16x8 a = load_frag(&Qs[(m0 + m) * PQ + t * 16 + h * 8]);
        s16x8 b = load_frag(&Gt[(n0 + m) * PQ + t * 16 + h * 8]);
        acc = __builtin_amdgcn_mfma_f32_32x32x16_bf16(a, b, acc, 0, 0, 0);
    }
    #pragma unroll
    for (int r = 0; r < 16; ++r) {
        const int row = (r & 3) + 8 * (r >> 2) + 4 * h;
        const int qi  = iqL[m0 + row];
        atomicAdd(&Ob[qi * D + n0 + m], acc[r]);      // duplicates in iq must accumulate
    }
}

extern "C" void kernel_launch(void* const* d_in, const int* in_sizes, int n_in,
                              void* d_out, int out_size, void* d_ws, size_t ws_size,
                              hipStream_t stream) {
    const float* Q  = (const float*)d_in[0];
    const float* V  = (const float*)d_in[2];
    const int*   iq = (const int*)d_in[4];
    const int*   ik = (const int*)d_in[5];
    float*       out = (float*)d_out;

    // ws layout (all overwritten every call; no zero-init needed):
    float*          Mp  = (float*)d_ws;                         // 32*32*4096 f32 = 16.8 MB
    float*          Cp  = Mp + (size_t)BH * SPA * 4096;         // 32*32*64 f32
    unsigned short* Qsw = (unsigned short*)(Cp + (size_t)BH * SPA * 64);  // 32*2048*64 bf16
    unsigned short* Gtw = Qsw + (size_t)BH * NSQ * 64;          // 32*4096 bf16

    hipMemsetAsync(d_out, 0, (size_t)out_size * sizeof(float), stream);
    kA<<<BH * SPA, 256, 0, stream>>>(Q, V, iq, ik, Mp, Cp, Qsw);
    kB<<<BH * 4, 256, 0, stream>>>(Mp, Cp, Gtw);
    kC<<<BH * SPC, 256, 0, stream>>>(V, iq, ik, Qsw, Gtw, out);
}